// Round 1
// baseline (619.288 us; speedup 1.0000x reference)
//
#include <hip/hip_runtime.h>
#include <math.h>

#define HID 128

static inline int ceil_div(int a, int b) { return (a + b - 1) / b; }

// ---------------- CSR build ----------------

__global__ void k_init_cnt(int* cnt, int n) {
    int i = blockIdx.x * blockDim.x + threadIdx.x;
    if (i < n) cnt[i] = 1;   // self-loop
}

__global__ void k_hist(const int* __restrict__ dst, int* cnt, int E) {
    int e = blockIdx.x * blockDim.x + threadIdx.x;
    if (e < E) atomicAdd(&cnt[dst[e]], 1);
}

__global__ void k_dinv(const int* __restrict__ cnt, float* dinv, int n) {
    int i = blockIdx.x * blockDim.x + threadIdx.x;
    if (i < n) dinv[i] = rsqrtf((float)cnt[i]);
}

__global__ __launch_bounds__(1024) void k_scan1(const int* __restrict__ cnt, int* incl, int* bsum, int n) {
    __shared__ int s[1024];
    int t = threadIdx.x;
    int i = blockIdx.x * 1024 + t;
    int x = (i < n) ? (cnt[i] - 1) : 0;
    s[t] = x;
    __syncthreads();
    for (int off = 1; off < 1024; off <<= 1) {
        int v = (t >= off) ? s[t - off] : 0;
        __syncthreads();
        s[t] += v;
        __syncthreads();
    }
    if (i < n) incl[i] = s[t];
    if (t == 1023) bsum[blockIdx.x] = s[1023];
}

__global__ void k_scan2(int* bsum, int nb) {
    if (blockIdx.x == 0 && threadIdx.x == 0) {
        int run = 0;
        for (int j = 0; j < nb; ++j) { int v = bsum[j]; bsum[j] = run; run += v; }
    }
}

__global__ void k_scan3(const int* __restrict__ cnt, const int* __restrict__ incl,
                        const int* __restrict__ bsum, int* rs, int* cur, int n) {
    int i = blockIdx.x * blockDim.x + threadIdx.x;
    if (i < n) {
        int x = cnt[i] - 1;
        int v = incl[i] - x + bsum[i >> 10];
        rs[i] = v;
        cur[i] = v;
    }
}

__global__ void k_fill(const int* __restrict__ ei, const float* __restrict__ dinv,
                       int* cur, int* colx, float* wgt, int E) {
    int e = blockIdx.x * blockDim.x + threadIdx.x;
    if (e < E) {
        int s = ei[e];
        int d = ei[E + e];
        int p = atomicAdd(&cur[d], 1);
        colx[p] = s;
        wgt[p] = dinv[s] * dinv[d];
    }
}

// ---------------- fp32 GEMM: C[n,128] = A[n,128] @ W[128,128] ----------------
// 64x64 tile per block (blockIdx.y = column half), A^T + W staged in LDS (padded stride 68).

__global__ __launch_bounds__(256) void k_gemm(const float* __restrict__ A, const float* __restrict__ W,
                                              float* __restrict__ C, int n) {
    __shared__ float sAT[128 * 68];
    __shared__ float sW[128 * 68];
    int tid = threadIdx.x;
    int rbase = blockIdx.x * 64;
    int cb = blockIdx.y;

    // stage A^T: sAT[k][r]
    for (int it = 0; it < 8; ++it) {
        int i = tid + it * 256;        // float4 index, 0..2047
        int r = i >> 5, kq = i & 31;
        float4 v = make_float4(0.f, 0.f, 0.f, 0.f);
        int row = rbase + r;
        if (row < n) v = *(const float4*)&A[(size_t)row * HID + kq * 4];
        int kb = kq * 4;
        sAT[(kb + 0) * 68 + r] = v.x;
        sAT[(kb + 1) * 68 + r] = v.y;
        sAT[(kb + 2) * 68 + r] = v.z;
        sAT[(kb + 3) * 68 + r] = v.w;
    }
    // stage W half: sW[k][c]   (c = cb*64 + 0..63)
    for (int it = 0; it < 8; ++it) {
        int i = tid + it * 256;        // float4 index, 0..2047
        int k = i >> 4, cq = i & 15;
        float4 v = *(const float4*)&W[k * HID + cb * 64 + cq * 4];
        *(float4*)&sW[k * 68 + cq * 4] = v;
    }
    __syncthreads();

    int tr = tid >> 4, tc = tid & 15;
    int r0 = tr * 4, c0 = tc * 4;
    float acc[4][4] = {};
#pragma unroll 8
    for (int k = 0; k < 128; ++k) {
        float4 a = *(const float4*)&sAT[k * 68 + r0];
        float4 w = *(const float4*)&sW[k * 68 + c0];
        acc[0][0] += a.x * w.x; acc[0][1] += a.x * w.y; acc[0][2] += a.x * w.z; acc[0][3] += a.x * w.w;
        acc[1][0] += a.y * w.x; acc[1][1] += a.y * w.y; acc[1][2] += a.y * w.z; acc[1][3] += a.y * w.w;
        acc[2][0] += a.z * w.x; acc[2][1] += a.z * w.y; acc[2][2] += a.z * w.z; acc[2][3] += a.z * w.w;
        acc[3][0] += a.w * w.x; acc[3][1] += a.w * w.y; acc[3][2] += a.w * w.z; acc[3][3] += a.w * w.w;
    }
    for (int i = 0; i < 4; ++i) {
        int row = rbase + r0 + i;
        if (row < n) {
            float4 o = make_float4(acc[i][0], acc[i][1], acc[i][2], acc[i][3]);
            *(float4*)&C[(size_t)row * HID + cb * 64 + c0] = o;
        }
    }
}

// ---------------- SpMM: out[ri] = relu( sum_e w_e * h[col_e] + dinv[row]^2 * h[row] + bias ) ----------------
// one wave per output row, lane handles 2 channels

__global__ __launch_bounds__(256) void k_spmm(const float* __restrict__ h, const int* __restrict__ rs,
                                              const int* __restrict__ cnt, const int* __restrict__ colx,
                                              const float* __restrict__ wgt, const float* __restrict__ dinv,
                                              const float* __restrict__ bias, float* __restrict__ out,
                                              const int* __restrict__ rowmap, int nrows) {
    int w = threadIdx.x >> 6;
    int lane = threadIdx.x & 63;
    int ri = blockIdx.x * 4 + w;
    if (ri >= nrows) return;
    int row = rowmap ? rowmap[ri] : ri;
    int p = rs[row];
    int pe = p + cnt[row] - 1;
    int c = lane * 2;
    float a0 = 0.f, a1 = 0.f;
    for (; p + 3 < pe; p += 4) {
        int s0 = colx[p], s1 = colx[p + 1], s2 = colx[p + 2], s3 = colx[p + 3];
        float w0 = wgt[p], w1 = wgt[p + 1], w2 = wgt[p + 2], w3 = wgt[p + 3];
        float2 h0 = *(const float2*)&h[(size_t)s0 * HID + c];
        float2 h1 = *(const float2*)&h[(size_t)s1 * HID + c];
        float2 h2 = *(const float2*)&h[(size_t)s2 * HID + c];
        float2 h3 = *(const float2*)&h[(size_t)s3 * HID + c];
        a0 += w0 * h0.x + w1 * h1.x + w2 * h2.x + w3 * h3.x;
        a1 += w0 * h0.y + w1 * h1.y + w2 * h2.y + w3 * h3.y;
    }
    for (; p < pe; ++p) {
        int s0 = colx[p];
        float w0 = wgt[p];
        float2 h0 = *(const float2*)&h[(size_t)s0 * HID + c];
        a0 += w0 * h0.x;
        a1 += w0 * h0.y;
    }
    float di = dinv[row];
    float d2 = di * di;
    float2 hs = *(const float2*)&h[(size_t)row * HID + c];
    a0 += d2 * hs.x + bias[c];
    a1 += d2 * hs.y + bias[c + 1];
    a0 = fmaxf(a0, 0.f);
    a1 = fmaxf(a1, 0.f);
    float2 o = make_float2(a0, a1);
    *(float2*)&out[(size_t)ri * HID + c] = o;
}

// ---------------- misc small kernels ----------------

__global__ void k_maskrows(float* P, const int* __restrict__ batch, int B) {
    int i = blockIdx.x * blockDim.x + threadIdx.x;
    if (i < B * 32) {
        int b = i >> 5, q = i & 31;
        int row = batch[b];
        *(float4*)&P[(size_t)row * HID + q * 4] = make_float4(0.f, 0.f, 0.f, 0.f);
    }
}

__global__ void k_y(const int* __restrict__ batch, const int* __restrict__ labels,
                    float* yv, float* pos_part, int B) {
    __shared__ float s[256];
    int t = threadIdx.x;
    int b = blockIdx.x * 256 + t;
    float y = 0.f;
    if (b < B) {
        y = (labels[batch[b]] == 1) ? 1.f : 0.f;
        yv[b] = y;
    }
    s[t] = y;
    __syncthreads();
    for (int st = 128; st > 0; st >>= 1) {
        if (t < st) s[t] += s[t + st];
        __syncthreads();
    }
    if (t == 0) pos_part[blockIdx.x] = s[0];
}

__global__ __launch_bounds__(256) void k_possum(const float* __restrict__ gf, const float* __restrict__ yv,
                                                float* pos_sum, int B) {
    __shared__ float s[256];
    int j = blockIdx.x;
    int t = threadIdx.x;
    float acc = 0.f;
    for (int b = t; b < B; b += 256) acc += yv[b] * gf[(size_t)b * HID + j];
    s[t] = acc;
    __syncthreads();
    for (int st = 128; st > 0; st >>= 1) {
        if (t < st) s[t] += s[t + st];
        __syncthreads();
    }
    if (t == 0) pos_sum[j] = s[0];
}

__global__ __launch_bounds__(128) void k_ctxvec(const float* __restrict__ Wctx, const float* __restrict__ pos_sum,
                                                const float* __restrict__ pos_part, float* v, float* pcnt, int npart) {
    __shared__ float sproto[128];
    __shared__ float spc;
    int t = threadIdx.x;
    if (t == 0) {
        float pc = 0.f;
        for (int i = 0; i < npart; ++i) pc += pos_part[i];
        spc = pc;
        pcnt[0] = pc;
    }
    __syncthreads();
    sproto[t] = pos_sum[t] / spc;
    __syncthreads();
    float acc = 0.f;
#pragma unroll 4
    for (int j = 0; j < 128; ++j) acc += Wctx[t * 128 + j] * sproto[j];
    v[t] = acc;
}

__global__ __launch_bounds__(128) void k_heads(const float* __restrict__ gf, const float* __restrict__ envf,
                                               const float* __restrict__ Wloc, const float* __restrict__ v,
                                               const float* __restrict__ yv, const float* __restrict__ bctx,
                                               const float* __restrict__ bloc, float* partA, float* partB, int B) {
    __shared__ float se[128];
    __shared__ float r1[128];
    __shared__ float r2[128];
    int b = blockIdx.x, t = threadIdx.x;
    float g = gf[(size_t)b * HID + t];
    float e = envf[(size_t)b * HID + t];
    se[t] = e;
    __syncthreads();
    float tmp = 0.f;
#pragma unroll 4
    for (int j = 0; j < 128; ++j) tmp += se[j] * Wloc[j * 128 + t];
    r1[t] = g * v[t];
    r2[t] = tmp * g;
    __syncthreads();
    for (int st = 64; st > 0; st >>= 1) {
        if (t < st) { r1[t] += r1[t + st]; r2[t] += r2[t + st]; }
        __syncthreads();
    }
    if (t == 0) {
        float y = yv[b];
        float z1 = r1[0] + bctx[0];
        float z2 = r2[0] + bloc[0];
        float l1 = fmaxf(z1, 0.f) + log1pf(expf(-fabsf(z1))) - z1 * y;
        float l2 = fmaxf(z2, 0.f) + log1pf(expf(-fabsf(z2))) - z2 * (1.f - y);
        partA[b] = l1;
        partB[b] = l2;
    }
}

__global__ __launch_bounds__(256) void k_final(const float* __restrict__ partA, const float* __restrict__ partB,
                                               const float* __restrict__ pcnt, float* out_loss, int B) {
    __shared__ float s1[256];
    __shared__ float s2[256];
    int t = threadIdx.x;
    float a = 0.f, b2 = 0.f;
    for (int i = t; i < B; i += 256) { a += partA[i]; b2 += partB[i]; }
    s1[t] = a;
    s2[t] = b2;
    __syncthreads();
    for (int st = 128; st > 0; st >>= 1) {
        if (t < st) { s1[t] += s1[t + st]; s2[t] += s2[t + st]; }
        __syncthreads();
    }
    if (t == 0) {
        float pc = pcnt[0];
        float nc = (float)B - pc;
        float total = 0.5f * (s1[0] / (float)B) + 0.5f * (s2[0] / (float)B);
        out_loss[0] = (pc > 0.f && nc > 0.f) ? total : 0.f;
    }
}

// ---------------- launcher ----------------

extern "C" void kernel_launch(void* const* d_in, const int* in_sizes, int n_in,
                              void* d_out, int out_size, void* d_ws, size_t ws_size,
                              hipStream_t stream) {
    const float* x      = (const float*)d_in[0];
    const int*   ei     = (const int*)d_in[1];
    const int*   batch  = (const int*)d_in[2];
    const int*   labels = (const int*)d_in[3];
    const float* W1     = (const float*)d_in[4];
    const float* b1     = (const float*)d_in[5];
    const float* W2     = (const float*)d_in[6];
    const float* b2     = (const float*)d_in[7];
    const float* Wctx   = (const float*)d_in[8];
    const float* bctx   = (const float*)d_in[9];
    const float* Wloc   = (const float*)d_in[10];
    const float* bloc   = (const float*)d_in[11];

    int N = in_sizes[0] / HID;
    int E = in_sizes[1] / 2;
    int B = in_sizes[2];
    float* out = (float*)d_out;

    char* wsb = (char*)d_ws;
    size_t off = 0;
    auto alloc = [&](size_t bytes) -> char* {
        char* p = wsb + off;
        off += (bytes + 255) & ~(size_t)255;
        return p;
    };
    float* P0   = (float*)alloc((size_t)N * HID * 4);
    float* Q1   = (float*)alloc((size_t)N * HID * 4);
    float* Q2   = (float*)alloc((size_t)N * HID * 4);
    int*   cnt  = (int*)alloc((size_t)N * 4);
    float* dinv = (float*)alloc((size_t)N * 4);
    int*   incl = (int*)alloc((size_t)N * 4);
    int*   rs   = (int*)alloc((size_t)N * 4);
    int*   cur  = (int*)alloc((size_t)N * 4);
    int*   bsum = (int*)alloc(256 * 4);
    int*   colx = (int*)alloc((size_t)E * 4);
    float* wgt  = (float*)alloc((size_t)E * 4);
    float* envf = (float*)alloc((size_t)B * HID * 4);
    float* yv   = (float*)alloc((size_t)B * 4);
    float* pos_part = (float*)alloc(64 * 4);
    float* pos_sum  = (float*)alloc(128 * 4);
    float* vvec     = (float*)alloc(128 * 4);
    float* pcnt     = (float*)alloc(256);
    float* partA    = (float*)alloc((size_t)B * 4);
    float* partB    = (float*)alloc((size_t)B * 4);
    (void)ws_size; (void)n_in; (void)out_size;

    const int* dstp = ei + E;
    int nb = ceil_div(N, 1024);

    // CSR build
    k_init_cnt<<<ceil_div(N, 256), 256, 0, stream>>>(cnt, N);
    k_hist<<<ceil_div(E, 256), 256, 0, stream>>>(dstp, cnt, E);
    k_dinv<<<ceil_div(N, 256), 256, 0, stream>>>(cnt, dinv, N);
    k_scan1<<<nb, 1024, 0, stream>>>(cnt, incl, bsum, N);
    k_scan2<<<1, 1, 0, stream>>>(bsum, nb);
    k_scan3<<<ceil_div(N, 256), 256, 0, stream>>>(cnt, incl, bsum, rs, cur, N);
    k_fill<<<ceil_div(E, 256), 256, 0, stream>>>(ei, dinv, cur, colx, wgt, E);

    dim3 ggrid(ceil_div(N, 64), 2);

    // normal pass
    k_gemm<<<ggrid, 256, 0, stream>>>(x, W1, P0, N);                                   // P1 = x@W1
    k_spmm<<<ceil_div(N, 4), 256, 0, stream>>>(P0, rs, cnt, colx, wgt, dinv, b1, Q1, nullptr, N);  // h1
    k_gemm<<<ggrid, 256, 0, stream>>>(Q1, W2, Q2, N);                                  // P2 = h1@W2
    k_spmm<<<ceil_div(B, 4), 256, 0, stream>>>(Q2, rs, cnt, colx, wgt, dinv, b2, out, batch, B);   // gf

    // environment pass (mask P1 in place)
    k_maskrows<<<ceil_div(B * 32, 256), 256, 0, stream>>>(P0, batch, B);
    k_spmm<<<ceil_div(N, 4), 256, 0, stream>>>(P0, rs, cnt, colx, wgt, dinv, b1, Q1, nullptr, N);  // e1
    k_gemm<<<ggrid, 256, 0, stream>>>(Q1, W2, Q2, N);                                  // P2e
    k_spmm<<<ceil_div(B, 4), 256, 0, stream>>>(Q2, rs, cnt, colx, wgt, dinv, b2, envf, batch, B);  // env_f

    // heads
    int nyb = ceil_div(B, 256);
    k_y<<<nyb, 256, 0, stream>>>(batch, labels, yv, pos_part, B);
    k_possum<<<128, 256, 0, stream>>>(out, yv, pos_sum, B);
    k_ctxvec<<<1, 128, 0, stream>>>(Wctx, pos_sum, pos_part, vvec, pcnt, nyb);
    k_heads<<<B, 128, 0, stream>>>(out, envf, Wloc, vvec, yv, bctx, bloc, partA, partB, B);
    k_final<<<1, 256, 0, stream>>>(partA, partB, pcnt, out + (size_t)B * HID, B);
}

// Round 2
// 318.945 us; speedup vs baseline: 1.9417x; 1.9417x over previous
//
#include <hip/hip_runtime.h>
#include <math.h>

#define HID 128
#define BSHIFT 8                 // 256 nodes per bucket
#define NBUCK_MAX 256

typedef _Float16 h2v __attribute__((ext_vector_type(2)));
typedef _Float16 h8v __attribute__((ext_vector_type(8)));
typedef float f4v __attribute__((ext_vector_type(4)));

static inline int ceil_div(int a, int b) { return (a + b - 1) / b; }

// ---------------- init ----------------

__global__ void k_init(int* cnt, unsigned int* mask, int n, int mw) {
    int i = blockIdx.x * blockDim.x + threadIdx.x;
    if (i < n) cnt[i] = 1;   // self-loop
    if (i < mw) mask[i] = 0u;
}

__global__ void k_hist(const int* __restrict__ dst, int* cnt, int E) {
    int e = blockIdx.x * blockDim.x + threadIdx.x;
    if (e < E) atomicAdd(&cnt[dst[e]], 1);
}

__global__ void k_setbits(const int* __restrict__ batch, unsigned int* mask, int B) {
    int i = blockIdx.x * blockDim.x + threadIdx.x;
    if (i < B) { int nd = batch[i]; atomicOr(&mask[nd >> 5], 1u << (nd & 31)); }
}

__global__ void k_dinv(const int* __restrict__ cnt, float* dinv, int n) {
    int i = blockIdx.x * blockDim.x + threadIdx.x;
    if (i < n) dinv[i] = rsqrtf((float)cnt[i]);
}

// ---------------- scan (rs = exclusive prefix of degree) ----------------

__global__ __launch_bounds__(1024) void k_scan1(const int* __restrict__ cnt, int* incl, int* bsum, int n) {
    __shared__ int s[1024];
    int t = threadIdx.x;
    int i = blockIdx.x * 1024 + t;
    int x = (i < n) ? (cnt[i] - 1) : 0;
    s[t] = x;
    __syncthreads();
    for (int off = 1; off < 1024; off <<= 1) {
        int v = (t >= off) ? s[t - off] : 0;
        __syncthreads();
        s[t] += v;
        __syncthreads();
    }
    if (i < n) incl[i] = s[t];
    if (t == 1023) bsum[blockIdx.x] = s[1023];
}

__global__ void k_scan2(int* bsum, int nb) {
    if (blockIdx.x == 0 && threadIdx.x == 0) {
        int run = 0;
        for (int j = 0; j < nb; ++j) { int v = bsum[j]; bsum[j] = run; run += v; }
    }
}

__global__ void k_scan3(const int* __restrict__ cnt, const int* __restrict__ incl,
                        const int* __restrict__ bsum, int* rs, int* cur, int n) {
    int i = blockIdx.x * blockDim.x + threadIdx.x;
    if (i < n) {
        int x = cnt[i] - 1;
        int v = incl[i] - x + bsum[i >> 10];
        rs[i] = v;
        cur[i] = v;
    }
}

__global__ void k_bstart(const int* __restrict__ rs, int* bstart, int* bcur, int N, int NB, int E) {
    int b = threadIdx.x;
    if (b <= NB) {
        int n0 = b << BSHIFT;
        int v = (n0 < N) ? rs[n0] : E;
        bstart[b] = v;
        if (b < NB) bcur[b] = v;
    }
}

// ---------------- bucket partition (pass A) + local CSR fill (pass B) ----------------

__global__ __launch_bounds__(256) void k_partA(const int* __restrict__ ei, int* __restrict__ bcur,
                                               int2* __restrict__ ebuf, int E, int NB) {
    __shared__ int lcnt[NBUCK_MAX];
    __shared__ int lbase[NBUCK_MAX];
    int tid = threadIdx.x;
    if (tid < NB) lcnt[tid] = 0;
    __syncthreads();
    int base = blockIdx.x * 4096;
    int sv[16], dv[16];
#pragma unroll
    for (int j = 0; j < 16; ++j) {
        int e = base + tid + j * 256;
        if (e < E) {
            sv[j] = ei[e];
            dv[j] = ei[E + e];
            atomicAdd(&lcnt[dv[j] >> BSHIFT], 1);
        } else dv[j] = -1;
    }
    __syncthreads();
    if (tid < NB) {
        int cc = lcnt[tid];
        lbase[tid] = cc ? atomicAdd(&bcur[tid], cc) : 0;
        lcnt[tid] = 0;
    }
    __syncthreads();
#pragma unroll
    for (int j = 0; j < 16; ++j) {
        if (dv[j] >= 0) {
            int b = dv[j] >> BSHIFT;
            int r = atomicAdd(&lcnt[b], 1);
            ebuf[lbase[b] + r] = make_int2(sv[j], dv[j]);
        }
    }
}

__global__ __launch_bounds__(256) void k_partB(const int2* __restrict__ ebuf, const int* __restrict__ bstart,
                                               const float* __restrict__ dinv, int* __restrict__ cur,
                                               int2* __restrict__ csr) {
    int b = blockIdx.x >> 2, q = blockIdx.x & 3;
    int lo = bstart[b], hi = bstart[b + 1];
    int len = hi - lo;
    int i0 = lo + ((len * q) >> 2);
    int i1 = lo + ((len * (q + 1)) >> 2);
    for (int i = i0 + threadIdx.x; i < i1; i += 256) {
        int2 v = ebuf[i];
        int p = atomicAdd(&cur[v.y], 1);
        csr[p] = make_int2(v.x, __float_as_int(dinv[v.x] * dinv[v.y]));
    }
}

// ---------------- fp16 MFMA GEMM: C[n,128](fp16) = A[n,128] @ W[128,128](fp32) ----------------

template<int SRC_F32, int RELU>
__global__ __launch_bounds__(256) void k_gemm(const void* __restrict__ Av, const float* __restrict__ W,
                                              _Float16* __restrict__ C, int n) {
    __shared__ _Float16 sWT[128 * 136];   // W^T, padded stride 136 halves
    int tid = threadIdx.x;
#pragma unroll
    for (int it = 0; it < 64; ++it) {
        int idx = tid + it * 256;          // 0..16383
        int k = idx >> 7, cc = idx & 127;
        sWT[cc * 136 + k] = (_Float16)W[idx];
    }
    __syncthreads();
    int wave = tid >> 6, lane = tid & 63;
    int rl = lane & 15, g = lane >> 4;
    int r = blockIdx.x * 64 + wave * 16 + rl;
    bool rok = r < n;
    f4v acc[8];
#pragma unroll
    for (int cf = 0; cf < 8; ++cf) acc[cf] = (f4v){0.f, 0.f, 0.f, 0.f};
    const float* Af = (const float*)Av;
    const _Float16* Ah = (const _Float16*)Av;
#pragma unroll
    for (int kb = 0; kb < 4; ++kb) {
        int k0 = kb * 32 + g * 8;
        h8v a = {};
        if (rok) {
            if (SRC_F32) {
                const float* ap = &Af[(size_t)r * HID + k0];
#pragma unroll
                for (int j = 0; j < 8; ++j) a[j] = (_Float16)ap[j];
            } else {
                a = *(const h8v*)&Ah[(size_t)r * HID + k0];
                if (RELU) {
#pragma unroll
                    for (int j = 0; j < 8; ++j) a[j] = (a[j] > (_Float16)0) ? a[j] : (_Float16)0;
                }
            }
        }
#pragma unroll
        for (int cf = 0; cf < 8; ++cf) {
            h8v bv = *(const h8v*)&sWT[(cf * 16 + rl) * 136 + k0];
            acc[cf] = __builtin_amdgcn_mfma_f32_16x16x32_f16(a, bv, acc[cf], 0, 0, 0);
        }
    }
    // C/D: col = cf*16 + (lane&15); row = wavebase + (lane>>4)*4 + i   [verified layout]
    int rowb = blockIdx.x * 64 + wave * 16 + g * 4;
#pragma unroll
    for (int cf = 0; cf < 8; ++cf) {
#pragma unroll
        for (int i = 0; i < 4; ++i) {
            int row = rowb + i;
            if (row < n) C[(size_t)row * HID + cf * 16 + rl] = (_Float16)acc[cf][i];
        }
    }
}

// ---------------- layer-1 SpMM fused with env-delta: writes pre1 and e1=relu(pre1-delta) ----------------

__global__ __launch_bounds__(256) void k_spmm1(const _Float16* __restrict__ P, const int* __restrict__ rs,
                                               const int* __restrict__ cnt, const int2* __restrict__ csr,
                                               const float* __restrict__ dinv, const float* __restrict__ bias,
                                               const unsigned int* __restrict__ bmask,
                                               _Float16* __restrict__ pre1, _Float16* __restrict__ e1out, int N) {
    int w = threadIdx.x >> 6, lane = threadIdx.x & 63;
    int row = blockIdx.x * 4 + w;
    if (row >= N) return;
    int p = rs[row];
    int pe = p + cnt[row] - 1;
    int c = lane * 2;
    float a0 = 0.f, a1 = 0.f, ab0 = 0.f, ab1 = 0.f;
    for (; p + 3 < pe; p += 4) {
        int2 q0 = csr[p], q1 = csr[p + 1], q2 = csr[p + 2], q3 = csr[p + 3];
        h2v v0 = *(const h2v*)&P[(size_t)q0.x * HID + c];
        h2v v1 = *(const h2v*)&P[(size_t)q1.x * HID + c];
        h2v v2 = *(const h2v*)&P[(size_t)q2.x * HID + c];
        h2v v3 = *(const h2v*)&P[(size_t)q3.x * HID + c];
        float w0 = __int_as_float(q0.y), w1 = __int_as_float(q1.y);
        float w2 = __int_as_float(q2.y), w3 = __int_as_float(q3.y);
        float f00 = w0 * (float)v0[0], f01 = w0 * (float)v0[1];
        float f10 = w1 * (float)v1[0], f11 = w1 * (float)v1[1];
        float f20 = w2 * (float)v2[0], f21 = w2 * (float)v2[1];
        float f30 = w3 * (float)v3[0], f31 = w3 * (float)v3[1];
        a0 += (f00 + f10) + (f20 + f30);
        a1 += (f01 + f11) + (f21 + f31);
        if ((bmask[q0.x >> 5] >> (q0.x & 31)) & 1) { ab0 += f00; ab1 += f01; }
        if ((bmask[q1.x >> 5] >> (q1.x & 31)) & 1) { ab0 += f10; ab1 += f11; }
        if ((bmask[q2.x >> 5] >> (q2.x & 31)) & 1) { ab0 += f20; ab1 += f21; }
        if ((bmask[q3.x >> 5] >> (q3.x & 31)) & 1) { ab0 += f30; ab1 += f31; }
    }
    for (; p < pe; ++p) {
        int2 q0 = csr[p];
        h2v v0 = *(const h2v*)&P[(size_t)q0.x * HID + c];
        float w0 = __int_as_float(q0.y);
        float f00 = w0 * (float)v0[0], f01 = w0 * (float)v0[1];
        a0 += f00; a1 += f01;
        if ((bmask[q0.x >> 5] >> (q0.x & 31)) & 1) { ab0 += f00; ab1 += f01; }
    }
    float di = dinv[row], d2 = di * di;
    h2v vs = *(const h2v*)&P[(size_t)row * HID + c];
    float s0 = d2 * (float)vs[0], s1 = d2 * (float)vs[1];
    a0 += s0 + bias[c];
    a1 += s1 + bias[c + 1];
    if ((bmask[row >> 5] >> (row & 31)) & 1) { ab0 += s0; ab1 += s1; }
    *(h2v*)&pre1[(size_t)row * HID + c] = (h2v){(_Float16)a0, (_Float16)a1};
    *(h2v*)&e1out[(size_t)row * HID + c] =
        (h2v){(_Float16)fmaxf(a0 - ab0, 0.f), (_Float16)fmaxf(a1 - ab1, 0.f)};
}

// ---------------- layer-2 batch SpMM, both views fused ----------------

__global__ __launch_bounds__(256) void k_spmm2(const _Float16* __restrict__ P2, const _Float16* __restrict__ P2e,
                                               const int* __restrict__ rs, const int* __restrict__ cnt,
                                               const int2* __restrict__ csr, const float* __restrict__ dinv,
                                               const float* __restrict__ bias, const int* __restrict__ batch,
                                               float* __restrict__ gf, _Float16* __restrict__ envh, int B) {
    int w = threadIdx.x >> 6, lane = threadIdx.x & 63;
    int ri = blockIdx.x * 4 + w;
    if (ri >= B) return;
    int row = batch[ri];
    int p = rs[row];
    int pe = p + cnt[row] - 1;
    int c = lane * 2;
    float g0 = 0.f, g1 = 0.f, e0 = 0.f, e1 = 0.f;
    for (; p + 1 < pe; p += 2) {
        int2 q0 = csr[p], q1 = csr[p + 1];
        float w0 = __int_as_float(q0.y), w1 = __int_as_float(q1.y);
        h2v x0 = *(const h2v*)&P2[(size_t)q0.x * HID + c];
        h2v y0 = *(const h2v*)&P2e[(size_t)q0.x * HID + c];
        h2v x1 = *(const h2v*)&P2[(size_t)q1.x * HID + c];
        h2v y1 = *(const h2v*)&P2e[(size_t)q1.x * HID + c];
        g0 += w0 * (float)x0[0] + w1 * (float)x1[0];
        g1 += w0 * (float)x0[1] + w1 * (float)x1[1];
        e0 += w0 * (float)y0[0] + w1 * (float)y1[0];
        e1 += w0 * (float)y0[1] + w1 * (float)y1[1];
    }
    for (; p < pe; ++p) {
        int2 q0 = csr[p];
        float w0 = __int_as_float(q0.y);
        h2v x0 = *(const h2v*)&P2[(size_t)q0.x * HID + c];
        h2v y0 = *(const h2v*)&P2e[(size_t)q0.x * HID + c];
        g0 += w0 * (float)x0[0]; g1 += w0 * (float)x0[1];
        e0 += w0 * (float)y0[0]; e1 += w0 * (float)y0[1];
    }
    float di = dinv[row], d2 = di * di;
    h2v xs = *(const h2v*)&P2[(size_t)row * HID + c];
    h2v ys = *(const h2v*)&P2e[(size_t)row * HID + c];
    float bb0 = bias[c], bb1 = bias[c + 1];
    g0 = fmaxf(g0 + d2 * (float)xs[0] + bb0, 0.f);
    g1 = fmaxf(g1 + d2 * (float)xs[1] + bb1, 0.f);
    e0 = fmaxf(e0 + d2 * (float)ys[0] + bb0, 0.f);
    e1 = fmaxf(e1 + d2 * (float)ys[1] + bb1, 0.f);
    *(float2*)&gf[(size_t)ri * HID + c] = make_float2(g0, g1);
    *(h2v*)&envh[(size_t)ri * HID + c] = (h2v){(_Float16)e0, (_Float16)e1};
}

// ---------------- heads ----------------

__global__ void k_y(const int* __restrict__ batch, const int* __restrict__ labels,
                    float* yv, float* pos_part, int B) {
    __shared__ float s[256];
    int t = threadIdx.x;
    int b = blockIdx.x * 256 + t;
    float y = 0.f;
    if (b < B) {
        y = (labels[batch[b]] == 1) ? 1.f : 0.f;
        yv[b] = y;
    }
    s[t] = y;
    __syncthreads();
    for (int st = 128; st > 0; st >>= 1) {
        if (t < st) s[t] += s[t + st];
        __syncthreads();
    }
    if (t == 0) pos_part[blockIdx.x] = s[0];
}

__global__ __launch_bounds__(256) void k_possum(const float* __restrict__ gf, const float* __restrict__ yv,
                                                float* pos_sum, int B) {
    __shared__ float s[256];
    int j = blockIdx.x;
    int t = threadIdx.x;
    float acc = 0.f;
    for (int b = t; b < B; b += 256) acc += yv[b] * gf[(size_t)b * HID + j];
    s[t] = acc;
    __syncthreads();
    for (int st = 128; st > 0; st >>= 1) {
        if (t < st) s[t] += s[t + st];
        __syncthreads();
    }
    if (t == 0) pos_sum[j] = s[0];
}

__global__ __launch_bounds__(128) void k_ctxvec(const float* __restrict__ Wctx, const float* __restrict__ pos_sum,
                                                const float* __restrict__ pos_part, float* v, float* pcnt, int npart) {
    __shared__ float sproto[128];
    __shared__ float spc;
    int t = threadIdx.x;
    if (t == 0) {
        float pc = 0.f;
        for (int i = 0; i < npart; ++i) pc += pos_part[i];
        spc = pc;
        pcnt[0] = pc;
    }
    __syncthreads();
    sproto[t] = pos_sum[t] / spc;
    __syncthreads();
    float acc = 0.f;
#pragma unroll 4
    for (int j = 0; j < 128; ++j) acc += Wctx[t * 128 + j] * sproto[j];
    v[t] = acc;
}

__global__ __launch_bounds__(128) void k_heads(const float* __restrict__ gf, const _Float16* __restrict__ T,
                                               const float* __restrict__ v, const float* __restrict__ yv,
                                               const float* __restrict__ bctx, const float* __restrict__ bloc,
                                               float* partA, float* partB, int B) {
    __shared__ float r1[128];
    __shared__ float r2[128];
    int b = blockIdx.x, t = threadIdx.x;
    float g = gf[(size_t)b * HID + t];
    r1[t] = g * v[t];
    r2[t] = (float)T[(size_t)b * HID + t] * g;
    __syncthreads();
    for (int st = 64; st > 0; st >>= 1) {
        if (t < st) { r1[t] += r1[t + st]; r2[t] += r2[t + st]; }
        __syncthreads();
    }
    if (t == 0) {
        float y = yv[b];
        float z1 = r1[0] + bctx[0];
        float z2 = r2[0] + bloc[0];
        float l1 = fmaxf(z1, 0.f) + log1pf(expf(-fabsf(z1))) - z1 * y;
        float l2 = fmaxf(z2, 0.f) + log1pf(expf(-fabsf(z2))) - z2 * (1.f - y);
        partA[b] = l1;
        partB[b] = l2;
    }
}

__global__ __launch_bounds__(256) void k_final(const float* __restrict__ partA, const float* __restrict__ partB,
                                               const float* __restrict__ pcnt, float* out_loss, int B) {
    __shared__ float s1[256];
    __shared__ float s2[256];
    int t = threadIdx.x;
    float a = 0.f, b2 = 0.f;
    for (int i = t; i < B; i += 256) { a += partA[i]; b2 += partB[i]; }
    s1[t] = a;
    s2[t] = b2;
    __syncthreads();
    for (int st = 128; st > 0; st >>= 1) {
        if (t < st) { s1[t] += s1[t + st]; s2[t] += s2[t + st]; }
        __syncthreads();
    }
    if (t == 0) {
        float pc = pcnt[0];
        float nc = (float)B - pc;
        float total = 0.5f * (s1[0] / (float)B) + 0.5f * (s2[0] / (float)B);
        out_loss[0] = (pc > 0.f && nc > 0.f) ? total : 0.f;
    }
}

// ---------------- launcher ----------------

extern "C" void kernel_launch(void* const* d_in, const int* in_sizes, int n_in,
                              void* d_out, int out_size, void* d_ws, size_t ws_size,
                              hipStream_t stream) {
    const float* x      = (const float*)d_in[0];
    const int*   ei     = (const int*)d_in[1];
    const int*   batch  = (const int*)d_in[2];
    const int*   labels = (const int*)d_in[3];
    const float* W1     = (const float*)d_in[4];
    const float* b1     = (const float*)d_in[5];
    const float* W2     = (const float*)d_in[6];
    const float* b2     = (const float*)d_in[7];
    const float* Wctx   = (const float*)d_in[8];
    const float* bctx   = (const float*)d_in[9];
    const float* Wloc   = (const float*)d_in[10];
    const float* bloc   = (const float*)d_in[11];

    int N = in_sizes[0] / HID;
    int E = in_sizes[1] / 2;
    int B = in_sizes[2];
    float* out = (float*)d_out;

    char* wsb = (char*)d_ws;
    size_t off = 0;
    auto alloc = [&](size_t bytes) -> char* {
        char* p = wsb + off;
        off += (bytes + 255) & ~(size_t)255;
        return p;
    };
    _Float16* P    = (_Float16*)alloc((size_t)N * HID * 2);
    _Float16* pre1 = (_Float16*)alloc((size_t)N * HID * 2);
    _Float16* e1t  = (_Float16*)alloc((size_t)N * HID * 2);
    _Float16* P2   = (_Float16*)alloc((size_t)N * HID * 2);
    _Float16* P2e  = (_Float16*)alloc((size_t)N * HID * 2);
    int2*  ebuf = (int2*)alloc((size_t)E * 8);
    int2*  csr  = (int2*)alloc((size_t)E * 8);
    int*   cnt  = (int*)alloc((size_t)N * 4);
    float* dinv = (float*)alloc((size_t)N * 4);
    int*   incl = (int*)alloc((size_t)N * 4);
    int*   rs   = (int*)alloc((size_t)N * 4);
    int*   cur  = (int*)alloc((size_t)N * 4);
    int*   bsum = (int*)alloc(256 * 4);
    int*   bstart = (int*)alloc((NBUCK_MAX + 1) * 4);
    int*   bcur   = (int*)alloc(NBUCK_MAX * 4);
    unsigned int* mask = (unsigned int*)alloc((size_t)ceil_div(N, 32) * 4);
    _Float16* envh = (_Float16*)alloc((size_t)B * HID * 2);
    _Float16* Tt   = (_Float16*)alloc((size_t)B * HID * 2);
    float* yv   = (float*)alloc((size_t)B * 4);
    float* pos_part = (float*)alloc(64 * 4);
    float* pos_sum  = (float*)alloc(128 * 4);
    float* vvec     = (float*)alloc(128 * 4);
    float* pcnt     = (float*)alloc(256);
    float* partA    = (float*)alloc((size_t)B * 4);
    float* partB    = (float*)alloc((size_t)B * 4);
    (void)ws_size; (void)n_in; (void)out_size;

    const int* dstp = ei + E;
    int nb = ceil_div(N, 1024);
    int NB = ceil_div(N, 1 << BSHIFT);
    int mw = ceil_div(N, 32);

    // degree + flags + scan + bucket bases
    k_init<<<ceil_div(N, 256), 256, 0, stream>>>(cnt, mask, N, mw);
    k_hist<<<ceil_div(E, 256), 256, 0, stream>>>(dstp, cnt, E);
    k_setbits<<<ceil_div(B, 256), 256, 0, stream>>>(batch, mask, B);
    k_dinv<<<ceil_div(N, 256), 256, 0, stream>>>(cnt, dinv, N);
    k_scan1<<<nb, 1024, 0, stream>>>(cnt, incl, bsum, N);
    k_scan2<<<1, 1, 0, stream>>>(bsum, nb);
    k_scan3<<<ceil_div(N, 256), 256, 0, stream>>>(cnt, incl, bsum, rs, cur, N);
    k_bstart<<<1, 256, 0, stream>>>(rs, bstart, bcur, N, NB, E);

    // bucketed CSR build
    k_partA<<<ceil_div(E, 4096), 256, 0, stream>>>(ei, bcur, ebuf, E, NB);
    k_partB<<<NB * 4, 256, 0, stream>>>(ebuf, bstart, dinv, cur, csr);

    // layer 1 (normal + env fused)
    k_gemm<1, 0><<<ceil_div(N, 64), 256, 0, stream>>>(x, W1, P, N);
    k_spmm1<<<ceil_div(N, 4), 256, 0, stream>>>(P, rs, cnt, csr, dinv, b1, mask, pre1, e1t, N);

    // layer 2 linear (relu applied to pre1 on load)
    k_gemm<0, 1><<<ceil_div(N, 64), 256, 0, stream>>>(pre1, W2, P2, N);
    k_gemm<0, 0><<<ceil_div(N, 64), 256, 0, stream>>>(e1t, W2, P2e, N);

    // layer 2 aggregation at batch rows only (both views)
    k_spmm2<<<ceil_div(B, 4), 256, 0, stream>>>(P2, P2e, rs, cnt, csr, dinv, b2, batch, out, envh, B);

    // T = env @ Wloc  (replaces per-row Wloc reads in heads)
    k_gemm<0, 0><<<ceil_div(B, 64), 256, 0, stream>>>(envh, Wloc, Tt, B);

    // heads
    int nyb = ceil_div(B, 256);
    k_y<<<nyb, 256, 0, stream>>>(batch, labels, yv, pos_part, B);
    k_possum<<<128, 256, 0, stream>>>(out, yv, pos_sum, B);
    k_ctxvec<<<1, 128, 0, stream>>>(Wctx, pos_sum, pos_part, vvec, pcnt, nyb);
    k_heads<<<B, 128, 0, stream>>>(out, Tt, vvec, yv, bctx, bloc, partA, partB, B);
    k_final<<<1, 256, 0, stream>>>(partA, partB, pcnt, out + (size_t)B * HID, B);
}